// Round 1
// baseline (612.950 us; speedup 1.0000x reference)
//
#include <hip/hip_runtime.h>
#include <cstdint>
#include <cstddef>

typedef __bf16 bf16_t;
typedef __bf16 bf16x8 __attribute__((ext_vector_type(8)));
typedef __bf16 bf16x4 __attribute__((ext_vector_type(4)));
typedef float  f32x4  __attribute__((ext_vector_type(4)));

#define HEADS    8
#define DIM_HEAD 64
#define SLICE    32
#define DIMC     512      // DIM == INNER == 512
#define NCOL     1024     // q(0..255) | expk(256..511) | v(512..1023)
#define BATCH    8
#define NSEQ     8192
#define NTOK     65536

// ---------------------------------------------------------------------------
// Weight prep: WcT[col][cin] (bf16, transposed for B-frag reads) where
//   col<256   : q  = sum_d W_in[cin, h*64+d] * Wq[d,s]   (col = h*32+s)
//   col<512   : k  = ... Wk                              (col-256 = h*32+s)
//   col>=512  : v  = ... Wv                              (col-512 = h*64+c)
// bias_c[col] = same combination applied to b_in.
// ---------------------------------------------------------------------------
__device__ __forceinline__ float combine_col(const float* __restrict__ vec,
                                             const float* __restrict__ Wq,
                                             const float* __restrict__ Wk,
                                             const float* __restrict__ Wv, int col) {
  const float* Wm; int ldw, h, j;
  if (col < 256)      { h = col >> 5;        j = col & 31;        Wm = Wq; ldw = 32; }
  else if (col < 512) { h = (col-256) >> 5;  j = (col-256) & 31;  Wm = Wk; ldw = 32; }
  else                { h = (col-512) >> 6;  j = (col-512) & 63;  Wm = Wv; ldw = 64; }
  const float* v = vec + h * DIM_HEAD;
  float acc = 0.f;
  #pragma unroll 8
  for (int d = 0; d < DIM_HEAD; ++d) acc += v[d] * Wm[d * ldw + j];
  return acc;
}

__global__ void wprep_kernel(const float* __restrict__ W_in, const float* __restrict__ b_in,
                             const float* __restrict__ Wq,   const float* __restrict__ Wk,
                             const float* __restrict__ Wv,
                             bf16_t* __restrict__ WcT, float* __restrict__ bias_c) {
  const int T  = blockIdx.x * blockDim.x + threadIdx.x;
  const int NT = gridDim.x * blockDim.x;
  for (int idx = T; idx < NCOL * DIMC; idx += NT) {
    const int col = idx >> 9, cin = idx & 511;
    WcT[(size_t)col * DIMC + cin] =
        (bf16_t)combine_col(W_in + (size_t)cin * DIMC, Wq, Wk, Wv, col);
  }
  if (T < NCOL) bias_c[T] = combine_col(b_in, Wq, Wk, Wv, T);
}

__global__ void zero_kernel(float* __restrict__ p, int n) {
  for (int i = blockIdx.x * blockDim.x + threadIdx.x; i < n; i += gridDim.x * blockDim.x)
    p[i] = 0.f;
}

// ---------------------------------------------------------------------------
// Generic 128x128x(BK=64) MFMA GEMM, 4 waves (2x2 of 64x64), register staging.
// A: row-major [M,K] (fp32 with on-the-fly bf16 cast, or bf16). B given as
// B^T [N,K] bf16. EPI=1: bf16 store, exp() on cols [256,512) (k columns).
// EPI=0: fp32 store + bias. blockIdx.z batches via element strides.
// ---------------------------------------------------------------------------
template<bool A_F32, int EPI>
__global__ __launch_bounds__(256) void gemm_kernel(
    const void* __restrict__ Av, const bf16_t* __restrict__ Bt,
    void* __restrict__ Cv, const float* __restrict__ bias,
    int K, int lda, int ldc,
    size_t strideA, size_t strideB, size_t strideC)
{
  __shared__ bf16_t As[128][72];   // +8 bf16 pad: 144B rows -> conflict-free frags
  __shared__ bf16_t Bs[128][72];   // B^T tile: [n][k]
  const int tid  = threadIdx.x;
  const int m0   = blockIdx.y * 128;
  const int n0   = blockIdx.x * 128;
  const int bz   = blockIdx.z;
  const int wave = tid >> 6, lane = tid & 63;
  const int cg   = lane & 15, qd = lane >> 4;
  const int wm   = (wave & 1) * 64, wn = (wave >> 1) * 64;
  const int r    = tid >> 1, kb = (tid & 1) * 32;

  f32x4 acc[4][4];
  #pragma unroll
  for (int i = 0; i < 4; ++i)
    #pragma unroll
    for (int j = 0; j < 4; ++j) acc[i][j] = (f32x4){0.f, 0.f, 0.f, 0.f};

  const bf16_t* Bp = Bt + strideB * bz;

  for (int k0 = 0; k0 < K; k0 += 64) {
    __syncthreads();
    if constexpr (A_F32) {
      const float* A = (const float*)Av + strideA * bz;
      const float4* srcA = reinterpret_cast<const float4*>(A + (size_t)(m0 + r) * lda + (k0 + kb));
      float4 f[8];
      #pragma unroll
      for (int i = 0; i < 8; ++i) f[i] = srcA[i];
      #pragma unroll
      for (int g = 0; g < 4; ++g) {
        bf16x8 w;
        w[0] = (bf16_t)f[2*g].x;   w[1] = (bf16_t)f[2*g].y;
        w[2] = (bf16_t)f[2*g].z;   w[3] = (bf16_t)f[2*g].w;
        w[4] = (bf16_t)f[2*g+1].x; w[5] = (bf16_t)f[2*g+1].y;
        w[6] = (bf16_t)f[2*g+1].z; w[7] = (bf16_t)f[2*g+1].w;
        *reinterpret_cast<bf16x8*>(&As[r][kb + g * 8]) = w;
      }
    } else {
      const bf16_t* A = (const bf16_t*)Av + strideA * bz;
      const uint4* srcA = reinterpret_cast<const uint4*>(A + (size_t)(m0 + r) * lda + (k0 + kb));
      uint4* dstA = reinterpret_cast<uint4*>(&As[r][kb]);
      #pragma unroll
      for (int i = 0; i < 4; ++i) dstA[i] = srcA[i];
    }
    {
      const uint4* srcB = reinterpret_cast<const uint4*>(Bp + (size_t)(n0 + r) * K + (k0 + kb));
      uint4* dstB = reinterpret_cast<uint4*>(&Bs[r][kb]);
      #pragma unroll
      for (int i = 0; i < 4; ++i) dstB[i] = srcB[i];
    }
    __syncthreads();
    #pragma unroll
    for (int ks = 0; ks < 64; ks += 32) {
      bf16x8 af[4], bfr[4];
      #pragma unroll
      for (int i = 0; i < 4; ++i)
        af[i] = *reinterpret_cast<const bf16x8*>(&As[wm + 16*i + cg][ks + qd*8]);
      #pragma unroll
      for (int j = 0; j < 4; ++j)
        bfr[j] = *reinterpret_cast<const bf16x8*>(&Bs[wn + 16*j + cg][ks + qd*8]);
      #pragma unroll
      for (int i = 0; i < 4; ++i)
        #pragma unroll
        for (int j = 0; j < 4; ++j)
          acc[i][j] = __builtin_amdgcn_mfma_f32_16x16x32_bf16(af[i], bfr[j], acc[i][j], 0, 0, 0);
    }
  }

  #pragma unroll
  for (int j = 0; j < 4; ++j) {
    const int col = n0 + wn + 16 * j + cg;
    const float bv = bias[col];
    #pragma unroll
    for (int i = 0; i < 4; ++i) {
      #pragma unroll
      for (int rr = 0; rr < 4; ++rr) {
        const int row = m0 + wm + 16 * i + qd * 4 + rr;
        float v = acc[i][j][rr] + bv;
        if (EPI == 1) {
          if (col >= 256 && col < 512) v = __expf(v);   // exp(k): unnormalized softmax
          ((bf16_t*)Cv + strideC * bz)[(size_t)row * ldc + col] = (bf16_t)v;
        } else {
          ((float*)Cv + strideC * bz)[(size_t)row * ldc + col] = v;
        }
      }
    }
  }
}

// ---------------------------------------------------------------------------
// kv accumulation: per (b,h): num[s][c] = sum_n expk[n,s]*v[n,c]; den[s] = sum expk.
// Each wave owns the full 32x64 tile (lane: 8 s x 4 c), streams 128 tokens.
// ---------------------------------------------------------------------------
__global__ __launch_bounds__(256) void kv_accum_kernel(const bf16_t* __restrict__ qkv1,
                                                       float* __restrict__ kv_num,
                                                       float* __restrict__ kv_den) {
  const int chunk = blockIdx.x;                 // 16 chunks over NSEQ
  const int h = blockIdx.y, b = blockIdx.z;
  const int tid = threadIdx.x;
  const int wave = tid >> 6, lane = tid & 63;
  const int cgrp = lane & 15, sgrp = lane >> 4;
  const int c0 = cgrp * 4, s0 = sgrp * 8;

  float acc[8][4];
  float dacc[8];
  #pragma unroll
  for (int i = 0; i < 8; ++i) {
    dacc[i] = 0.f;
    #pragma unroll
    for (int j = 0; j < 4; ++j) acc[i][j] = 0.f;
  }

  const int nbase = chunk * 512 + wave * 128;
  const bf16_t* base = qkv1 + ((size_t)(b * NSEQ + nbase)) * NCOL;
  const int ek_off = 256 + h * SLICE + s0;
  const int v_off  = 512 + h * DIM_HEAD + c0;

  #pragma unroll 4
  for (int n = 0; n < 128; ++n) {
    const bf16_t* rowp = base + (size_t)n * NCOL;
    bf16x8 ek = *reinterpret_cast<const bf16x8*>(rowp + ek_off);
    bf16x4 vv = *reinterpret_cast<const bf16x4*>(rowp + v_off);
    float ekf[8], vf[4];
    #pragma unroll
    for (int i = 0; i < 8; ++i) ekf[i] = (float)ek[i];
    #pragma unroll
    for (int j = 0; j < 4; ++j) vf[j] = (float)vv[j];
    #pragma unroll
    for (int i = 0; i < 8; ++i) {
      dacc[i] += ekf[i];
      #pragma unroll
      for (int j = 0; j < 4; ++j) acc[i][j] += ekf[i] * vf[j];
    }
  }

  __shared__ float red[4][SLICE][DIM_HEAD];   // 32 KB
  __shared__ float redd[4][SLICE];
  #pragma unroll
  for (int i = 0; i < 8; ++i)
    #pragma unroll
    for (int j = 0; j < 4; ++j) red[wave][s0 + i][c0 + j] = acc[i][j];
  if (cgrp == 0) {
    #pragma unroll
    for (int i = 0; i < 8; ++i) redd[wave][s0 + i] = dacc[i];
  }
  __syncthreads();
  float* dstn = kv_num + (size_t)(b * HEADS + h) * (SLICE * DIM_HEAD);
  for (int t = tid; t < SLICE * DIM_HEAD; t += 256) {
    const int s = t >> 6, c = t & 63;
    atomicAdd(&dstn[t], red[0][s][c] + red[1][s][c] + red[2][s][c] + red[3][s][c]);
  }
  if (tid < SLICE)
    atomicAdd(&kv_den[(b * HEADS + h) * SLICE + tid],
              redd[0][tid] + redd[1][tid] + redd[2][tid] + redd[3][tid]);
}

// ---------------------------------------------------------------------------
// In-place softmax over the 32 q-slices per (token, head).
// ---------------------------------------------------------------------------
__global__ __launch_bounds__(256) void softmax_q_kernel(bf16_t* __restrict__ qkv1) {
  const int T = blockIdx.x * 256 + threadIdx.x;       // NTOK*HEADS threads
  const int token = T >> 3, h = T & 7;
  bf16_t* p = qkv1 + (size_t)token * NCOL + h * SLICE;
  bf16x8 d[4];
  #pragma unroll
  for (int i = 0; i < 4; ++i) d[i] = reinterpret_cast<const bf16x8*>(p)[i];
  float f[32];
  #pragma unroll
  for (int i = 0; i < 4; ++i)
    #pragma unroll
    for (int j = 0; j < 8; ++j) f[i * 8 + j] = (float)d[i][j];
  float m = f[0];
  #pragma unroll
  for (int i = 1; i < 32; ++i) m = fmaxf(m, f[i]);
  float s = 0.f;
  #pragma unroll
  for (int i = 0; i < 32; ++i) { f[i] = __expf(f[i] - m); s += f[i]; }
  const float rs = 1.f / s;
  #pragma unroll
  for (int i = 0; i < 4; ++i) {
    bf16x8 w;
    #pragma unroll
    for (int j = 0; j < 8; ++j) w[j] = (bf16_t)(f[i * 8 + j] * rs);
    reinterpret_cast<bf16x8*>(p)[i] = w;
  }
}

// ---------------------------------------------------------------------------
// M prep: Mt[b][outc][h*32+s] = sum_c (kv_num[b,h,s,c]/den[b,h,s]) * W_out[h*64+c][outc]
// One block per (b,h); 512 threads = one per outc.
// ---------------------------------------------------------------------------
__global__ __launch_bounds__(512) void mprep_kernel(const float* __restrict__ kv_num,
                                                    const float* __restrict__ kv_den,
                                                    const float* __restrict__ W_out,
                                                    bf16_t* __restrict__ Mt) {
  const int bh = blockIdx.x, b = bh >> 3, h = bh & 7;
  const int tid = threadIdx.x;
  __shared__ float kvn[SLICE][DIM_HEAD];   // 8 KB (normalized kv)
  __shared__ float wbuf[8][DIMC];          // 16 KB
  const float* src = kv_num + (size_t)bh * (SLICE * DIM_HEAD);
  for (int t = tid; t < SLICE * DIM_HEAD; t += 512)
    kvn[t >> 6][t & 63] = src[t] / kv_den[bh * SLICE + (t >> 6)];
  float accs[SLICE];
  #pragma unroll
  for (int s = 0; s < SLICE; ++s) accs[s] = 0.f;
  for (int cb = 0; cb < DIM_HEAD; cb += 8) {
    __syncthreads();
    for (int t = tid; t < 8 * DIMC; t += 512)
      wbuf[t >> 9][t & 511] = W_out[(size_t)(h * DIM_HEAD + cb + (t >> 9)) * DIMC + (t & 511)];
    __syncthreads();
    #pragma unroll
    for (int cc = 0; cc < 8; ++cc) {
      const float wv = wbuf[cc][tid];
      #pragma unroll
      for (int s = 0; s < SLICE; ++s) accs[s] += kvn[s][cb + cc] * wv;
    }
  }
  bf16_t* dst = Mt + (size_t)b * (DIMC * 256) + (size_t)tid * 256 + h * SLICE;
  #pragma unroll
  for (int s = 0; s < SLICE; ++s) dst[s] = (bf16_t)accs[s];
}

// ---------------------------------------------------------------------------
extern "C" void kernel_launch(void* const* d_in, const int* in_sizes, int n_in,
                              void* d_out, int out_size, void* d_ws, size_t ws_size,
                              hipStream_t stream) {
  const float* x     = (const float*)d_in[0];
  const float* W_in  = (const float*)d_in[1];
  const float* b_in  = (const float*)d_in[2];
  const float* Wq    = (const float*)d_in[3];
  const float* Wk    = (const float*)d_in[4];
  const float* Wv    = (const float*)d_in[5];
  const float* W_out = (const float*)d_in[6];
  const float* b_out = (const float*)d_in[7];
  float* out = (float*)d_out;

  uint8_t* ws = (uint8_t*)d_ws;
  bf16_t* qkv1   = (bf16_t*)(ws);                      // 65536*1024 bf16 = 134217728 B
  bf16_t* WcT    = (bf16_t*)(ws + 134217728ull);       // 1024*512 bf16  = 1048576 B
  float*  bias_c = (float*) (ws + 135266304ull);       // 1024 f32       = 4096 B
  float*  kv_num = (float*) (ws + 135270400ull);       // 8*8*32*64 f32  = 524288 B
  float*  kv_den = (float*) (ws + 135794688ull);       // 8*8*32 f32     = 8192 B
  bf16_t* Mt     = (bf16_t*)(ws + 135802880ull);       // 8*512*256 bf16 = 2097152 B
                                                       // total 137900032 B

  wprep_kernel<<<dim3(128), dim3(256), 0, stream>>>(W_in, b_in, Wq, Wk, Wv, WcT, bias_c);
  zero_kernel<<<dim3(128), dim3(256), 0, stream>>>(kv_num, 133120 /* kv_num + kv_den floats */);

  // GEMM1: [65536,512](f32) @ WcT -> qkv1 [65536,1024] bf16 (exp on k cols)
  gemm_kernel<true, 1><<<dim3(8, 512, 1), dim3(256), 0, stream>>>(
      (const void*)x, WcT, (void*)qkv1, bias_c,
      512 /*K*/, 512 /*lda*/, NCOL /*ldc*/, (size_t)0, (size_t)0, (size_t)0);

  kv_accum_kernel<<<dim3(16, HEADS, BATCH), dim3(256), 0, stream>>>(qkv1, kv_num, kv_den);
  softmax_q_kernel<<<dim3(NTOK * HEADS / 256), dim3(256), 0, stream>>>(qkv1);
  mprep_kernel<<<dim3(BATCH * HEADS), dim3(512), 0, stream>>>(kv_num, kv_den, W_out, Mt);

  // GEMM3 (batched over b): qs [8192,256](bf16, lda=1024) @ Mt[b] -> out [8192,512] f32
  gemm_kernel<false, 0><<<dim3(4, 64, BATCH), dim3(256), 0, stream>>>(
      (const void*)qkv1, Mt, (void*)out, b_out,
      256 /*K*/, NCOL /*lda*/, DIMC /*ldc*/,
      (size_t)NSEQ * NCOL, (size_t)DIMC * 256, (size_t)NSEQ * DIMC);
}

// Round 2
// 529.627 us; speedup vs baseline: 1.1573x; 1.1573x over previous
//
#include <hip/hip_runtime.h>
#include <cstdint>
#include <cstddef>

typedef __bf16 bf16_t;
typedef __bf16 bf16x8 __attribute__((ext_vector_type(8)));
typedef __bf16 bf16x4 __attribute__((ext_vector_type(4)));
typedef float  f32x4  __attribute__((ext_vector_type(4)));

#define HEADS    8
#define DIM_HEAD 64
#define SLICE    32
#define DIMC     512      // DIM == INNER == 512
#define NCOL     1024     // q(0..255) | expk(256..511) | v(512..1023)
#define BATCH    8
#define NSEQ     8192
#define NTOK     65536

// Async global->LDS, 16B per lane. LDS dest is wave-uniform base + lane*16;
// our lds ptr is exactly base + lane*16 so readfirstlane(base) is correct.
__device__ __forceinline__ void gl2lds16(const bf16_t* g, bf16_t* l) {
  __builtin_amdgcn_global_load_lds(
      (const __attribute__((address_space(1))) uint32_t*)g,
      (__attribute__((address_space(3))) uint32_t*)l, 16, 0, 0);
}

// ---------------------------------------------------------------------------
// x fp32 -> bf16 (xb lives in d_out scratch; dead before GEMM3 writes out)
// ---------------------------------------------------------------------------
__global__ __launch_bounds__(256) void xcast_kernel(const float* __restrict__ x,
                                                    bf16_t* __restrict__ xb) {
  const size_t i = ((size_t)blockIdx.x * 256 + threadIdx.x) * 8;
  const float4 a = *reinterpret_cast<const float4*>(x + i);
  const float4 b = *reinterpret_cast<const float4*>(x + i + 4);
  bf16x8 w;
  w[0] = (bf16_t)a.x; w[1] = (bf16_t)a.y; w[2] = (bf16_t)a.z; w[3] = (bf16_t)a.w;
  w[4] = (bf16_t)b.x; w[5] = (bf16_t)b.y; w[6] = (bf16_t)b.z; w[7] = (bf16_t)b.w;
  *reinterpret_cast<bf16x8*>(xb + i) = w;
}

// ---------------------------------------------------------------------------
// Weight prep: WcT[col][cin] (bf16) with Wq/Wk/Wv cached in LDS, float4 W_in.
// ---------------------------------------------------------------------------
__global__ __launch_bounds__(256) void wprep_kernel(
    const float* __restrict__ W_in, const float* __restrict__ b_in,
    const float* __restrict__ Wq,   const float* __restrict__ Wk,
    const float* __restrict__ Wv,
    bf16_t* __restrict__ WcT, float* __restrict__ bias_c) {
  __shared__ float sW[8192];                 // Wq[0..2048) Wk[2048..4096) Wv[4096..8192)
  for (int t = threadIdx.x; t < 2048; t += 256) { sW[t] = Wq[t]; sW[2048 + t] = Wk[t]; }
  for (int t = threadIdx.x; t < 4096; t += 256) sW[4096 + t] = Wv[t];
  __syncthreads();

  const int T  = blockIdx.x * 256 + threadIdx.x;
  const int NT = gridDim.x * 256;
  for (int idx = T; idx < NCOL * DIMC; idx += NT) {
    const int col = idx >> 9, cin = idx & 511;
    int base, ldw, h, j;
    if (col < 256)      { h = col >> 5;       j = col & 31;       base = 0;    ldw = 32; }
    else if (col < 512) { h = (col-256) >> 5; j = (col-256) & 31; base = 2048; ldw = 32; }
    else                { h = (col-512) >> 6; j = (col-512) & 63; base = 4096; ldw = 64; }
    const float4* vp = reinterpret_cast<const float4*>(W_in + (size_t)cin * DIMC + h * DIM_HEAD);
    float acc = 0.f;
    #pragma unroll
    for (int d4 = 0; d4 < 16; ++d4) {
      const float4 v = vp[d4];
      acc += v.x * sW[base + (4*d4+0)*ldw + j];
      acc += v.y * sW[base + (4*d4+1)*ldw + j];
      acc += v.z * sW[base + (4*d4+2)*ldw + j];
      acc += v.w * sW[base + (4*d4+3)*ldw + j];
    }
    WcT[(size_t)col * DIMC + cin] = (bf16_t)acc;
  }
  if (T < NCOL) {
    const int col = T;
    int base, ldw, h, j;
    if (col < 256)      { h = col >> 5;       j = col & 31;       base = 0;    ldw = 32; }
    else if (col < 512) { h = (col-256) >> 5; j = (col-256) & 31; base = 2048; ldw = 32; }
    else                { h = (col-512) >> 6; j = (col-512) & 63; base = 4096; ldw = 64; }
    const float* vec = b_in + h * DIM_HEAD;
    float acc = 0.f;
    #pragma unroll 8
    for (int d = 0; d < DIM_HEAD; ++d) acc += vec[d] * sW[base + d * ldw + j];
    bias_c[col] = acc;
  }
}

// ---------------------------------------------------------------------------
// 128x128xBK64 MFMA GEMM, m97 structure: global_load_lds(16B) staging into
// unpadded LDS with XOR column-chunk swizzle (frag ds_read_b128 -> 2-way=free).
// A row-major bf16 [M,K]; B given as B^T [N,K] bf16.
// EPI=1: bf16 store, exp() on cols [256,512). EPI=0: fp32 store + bias.
// ---------------------------------------------------------------------------
template<int EPI>
__global__ __launch_bounds__(256) void gemm_kernel(
    const bf16_t* __restrict__ A, const bf16_t* __restrict__ Bt,
    void* __restrict__ Cv, const float* __restrict__ bias,
    int K, int lda, int ldc,
    size_t strideA, size_t strideB, size_t strideC)
{
  __shared__ bf16_t As[128 * 64];   // unpadded: required by global_load_lds
  __shared__ bf16_t Bs[128 * 64];
  const int tid  = threadIdx.x;
  const int m0   = blockIdx.y * 128;
  const int n0   = blockIdx.x * 128;
  const int bz   = blockIdx.z;
  const int wave = tid >> 6, lane = tid & 63;
  const int cg   = lane & 15, qd = lane >> 4;
  const int wm   = (wave & 1) * 64, wn = (wave >> 1) * 64;
  // staging: chunk c = wave*4+i covers rows [c*8,c*8+8); lane -> row c*8+(lane>>3),
  // global 16B col-chunk gchunk = (lane&7) ^ (row&7)  (XOR swizzle)
  const int srow   = lane >> 3;
  const int gchunk = (lane & 7) ^ srow;
  const int chb    = cg & 7;

  const bf16_t* Ab = A  + strideA * bz;
  const bf16_t* Bb = Bt + strideB * bz;

  f32x4 acc[4][4];
  #pragma unroll
  for (int i = 0; i < 4; ++i)
    #pragma unroll
    for (int j = 0; j < 4; ++j) acc[i][j] = (f32x4){0.f, 0.f, 0.f, 0.f};

  for (int k0 = 0; k0 < K; k0 += 64) {
    __syncthreads();
    #pragma unroll
    for (int i = 0; i < 4; ++i) {
      const int c = wave * 4 + i;
      const int row = c * 8 + srow;
      gl2lds16(Ab + (size_t)(m0 + row) * lda + k0 + gchunk * 8, As + c * 512 + lane * 8);
    }
    #pragma unroll
    for (int i = 0; i < 4; ++i) {
      const int c = wave * 4 + i;
      const int row = c * 8 + srow;
      gl2lds16(Bb + (size_t)(n0 + row) * K + k0 + gchunk * 8, Bs + c * 512 + lane * 8);
    }
    __syncthreads();   // compiler emits vmcnt(0) drain here (m97 structure)
    #pragma unroll
    for (int ks = 0; ks < 64; ks += 32) {
      const int k4 = ks >> 3;          // 0 or 4 (16B chunks)
      bf16x8 af[4], bfr[4];
      #pragma unroll
      for (int i = 0; i < 4; ++i) {
        const int ch = (qd + k4) ^ chb;
        af[i] = *reinterpret_cast<const bf16x8*>(As + (wm + 16*i + cg) * 64 + ch * 8);
      }
      #pragma unroll
      for (int j = 0; j < 4; ++j) {
        const int ch = (qd + k4) ^ chb;
        bfr[j] = *reinterpret_cast<const bf16x8*>(Bs + (wn + 16*j + cg) * 64 + ch * 8);
      }
      #pragma unroll
      for (int i = 0; i < 4; ++i)
        #pragma unroll
        for (int j = 0; j < 4; ++j)
          acc[i][j] = __builtin_amdgcn_mfma_f32_16x16x32_bf16(af[i], bfr[j], acc[i][j], 0, 0, 0);
    }
  }

  #pragma unroll
  for (int j = 0; j < 4; ++j) {
    const int col = n0 + wn + 16 * j + cg;
    const float bv = bias[col];
    #pragma unroll
    for (int i = 0; i < 4; ++i) {
      #pragma unroll
      for (int rr = 0; rr < 4; ++rr) {
        const int row = m0 + wm + 16 * i + qd * 4 + rr;
        float v = acc[i][j][rr] + bv;
        if (EPI == 1) {
          if (col >= 256 && col < 512) v = __expf(v);   // exp(k): unnormalized softmax
          ((bf16_t*)Cv + strideC * bz)[(size_t)row * ldc + col] = (bf16_t)v;
        } else {
          ((float*)Cv + strideC * bz)[(size_t)row * ldc + col] = v;
        }
      }
    }
  }
}

// ---------------------------------------------------------------------------
// kv accumulation: per (b,h): num[s][c] = sum_n expk[n,s]*v[n,c]; den[s] = sum expk.
// ---------------------------------------------------------------------------
__global__ __launch_bounds__(256) void kv_accum_kernel(const bf16_t* __restrict__ qkv1,
                                                       float* __restrict__ kv_num,
                                                       float* __restrict__ kv_den) {
  const int chunk = blockIdx.x;                 // 16 chunks over NSEQ
  const int h = blockIdx.y, b = blockIdx.z;
  const int tid = threadIdx.x;
  const int wave = tid >> 6, lane = tid & 63;
  const int cgrp = lane & 15, sgrp = lane >> 4;
  const int c0 = cgrp * 4, s0 = sgrp * 8;

  float acc[8][4];
  float dacc[8];
  #pragma unroll
  for (int i = 0; i < 8; ++i) {
    dacc[i] = 0.f;
    #pragma unroll
    for (int j = 0; j < 4; ++j) acc[i][j] = 0.f;
  }

  const int nbase = chunk * 512 + wave * 128;
  const bf16_t* base = qkv1 + ((size_t)(b * NSEQ + nbase)) * NCOL;
  const int ek_off = 256 + h * SLICE + s0;
  const int v_off  = 512 + h * DIM_HEAD + c0;

  #pragma unroll 4
  for (int n = 0; n < 128; ++n) {
    const bf16_t* rowp = base + (size_t)n * NCOL;
    bf16x8 ek = *reinterpret_cast<const bf16x8*>(rowp + ek_off);
    bf16x4 vv = *reinterpret_cast<const bf16x4*>(rowp + v_off);
    float ekf[8], vf[4];
    #pragma unroll
    for (int i = 0; i < 8; ++i) ekf[i] = (float)ek[i];
    #pragma unroll
    for (int j = 0; j < 4; ++j) vf[j] = (float)vv[j];
    #pragma unroll
    for (int i = 0; i < 8; ++i) {
      dacc[i] += ekf[i];
      #pragma unroll
      for (int j = 0; j < 4; ++j) acc[i][j] += ekf[i] * vf[j];
    }
  }

  __shared__ float red[4][SLICE][DIM_HEAD];   // 32 KB
  __shared__ float redd[4][SLICE];
  #pragma unroll
  for (int i = 0; i < 8; ++i)
    #pragma unroll
    for (int j = 0; j < 4; ++j) red[wave][s0 + i][c0 + j] = acc[i][j];
  if (cgrp == 0) {
    #pragma unroll
    for (int i = 0; i < 8; ++i) redd[wave][s0 + i] = dacc[i];
  }
  __syncthreads();
  float* dstn = kv_num + (size_t)(b * HEADS + h) * (SLICE * DIM_HEAD);
  for (int t = tid; t < SLICE * DIM_HEAD; t += 256) {
    const int s = t >> 6, c = t & 63;
    atomicAdd(&dstn[t], red[0][s][c] + red[1][s][c] + red[2][s][c] + red[3][s][c]);
  }
  if (tid < SLICE)
    atomicAdd(&kv_den[(b * HEADS + h) * SLICE + tid],
              redd[0][tid] + redd[1][tid] + redd[2][tid] + redd[3][tid]);
}

// ---------------------------------------------------------------------------
// In-place softmax over the 32 q-slices per (token, head).
// ---------------------------------------------------------------------------
__global__ __launch_bounds__(256) void softmax_q_kernel(bf16_t* __restrict__ qkv1) {
  const int T = blockIdx.x * 256 + threadIdx.x;       // NTOK*HEADS threads
  const int token = T >> 3, h = T & 7;
  bf16_t* p = qkv1 + (size_t)token * NCOL + h * SLICE;
  bf16x8 d[4];
  #pragma unroll
  for (int i = 0; i < 4; ++i) d[i] = reinterpret_cast<const bf16x8*>(p)[i];
  float f[32];
  #pragma unroll
  for (int i = 0; i < 4; ++i)
    #pragma unroll
    for (int j = 0; j < 8; ++j) f[i * 8 + j] = (float)d[i][j];
  float m = f[0];
  #pragma unroll
  for (int i = 1; i < 32; ++i) m = fmaxf(m, f[i]);
  float s = 0.f;
  #pragma unroll
  for (int i = 0; i < 32; ++i) { f[i] = __expf(f[i] - m); s += f[i]; }
  const float rs = 1.f / s;
  #pragma unroll
  for (int i = 0; i < 4; ++i) {
    bf16x8 w;
    #pragma unroll
    for (int j = 0; j < 8; ++j) w[j] = (bf16_t)(f[i * 8 + j] * rs);
    reinterpret_cast<bf16x8*>(p)[i] = w;
  }
}

// ---------------------------------------------------------------------------
// M prep: Mt[b][outc][h*32+s] = sum_c (kv_num/den) * W_out[h*64+c][outc]
// ---------------------------------------------------------------------------
__global__ __launch_bounds__(512) void mprep_kernel(const float* __restrict__ kv_num,
                                                    const float* __restrict__ kv_den,
                                                    const float* __restrict__ W_out,
                                                    bf16_t* __restrict__ Mt) {
  const int bh = blockIdx.x, b = bh >> 3, h = bh & 7;
  const int tid = threadIdx.x;
  __shared__ float kvn[SLICE][DIM_HEAD];   // 8 KB (normalized kv)
  __shared__ float wbuf[8][DIMC];          // 16 KB
  const float* src = kv_num + (size_t)bh * (SLICE * DIM_HEAD);
  for (int t = tid; t < SLICE * DIM_HEAD; t += 512)
    kvn[t >> 6][t & 63] = src[t] / kv_den[bh * SLICE + (t >> 6)];
  float accs[SLICE];
  #pragma unroll
  for (int s = 0; s < SLICE; ++s) accs[s] = 0.f;
  for (int cb = 0; cb < DIM_HEAD; cb += 8) {
    __syncthreads();
    for (int t = tid; t < 8 * DIMC; t += 512)
      wbuf[t >> 9][t & 511] = W_out[(size_t)(h * DIM_HEAD + cb + (t >> 9)) * DIMC + (t & 511)];
    __syncthreads();
    #pragma unroll
    for (int cc = 0; cc < 8; ++cc) {
      const float wv = wbuf[cc][tid];
      #pragma unroll
      for (int s = 0; s < SLICE; ++s) accs[s] += kvn[s][cb + cc] * wv;
    }
  }
  bf16_t* dst = Mt + (size_t)b * (DIMC * 256) + (size_t)tid * 256 + h * SLICE;
  #pragma unroll
  for (int s = 0; s < SLICE; ++s) dst[s] = (bf16_t)accs[s];
}

// ---------------------------------------------------------------------------
extern "C" void kernel_launch(void* const* d_in, const int* in_sizes, int n_in,
                              void* d_out, int out_size, void* d_ws, size_t ws_size,
                              hipStream_t stream) {
  const float* x     = (const float*)d_in[0];
  const float* W_in  = (const float*)d_in[1];
  const float* b_in  = (const float*)d_in[2];
  const float* Wq    = (const float*)d_in[3];
  const float* Wk    = (const float*)d_in[4];
  const float* Wv    = (const float*)d_in[5];
  const float* W_out = (const float*)d_in[6];
  const float* b_out = (const float*)d_in[7];
  float* out = (float*)d_out;

  uint8_t* ws = (uint8_t*)d_ws;
  bf16_t* qkv1   = (bf16_t*)(ws);                      // 65536*1024 bf16 = 134217728 B
  bf16_t* WcT    = (bf16_t*)(ws + 134217728ull);       // 1024*512 bf16  = 1048576 B
  float*  bias_c = (float*) (ws + 135266304ull);       // 1024 f32       = 4096 B
  float*  kv_num = (float*) (ws + 135270400ull);       // 8*8*32*64 f32  = 524288 B
  float*  kv_den = (float*) (ws + 135794688ull);       // 8*8*32 f32     = 8192 B
  bf16_t* Mt     = (bf16_t*)(ws + 135802880ull);       // 8*512*256 bf16 = 2097152 B
                                                       // total 137900032 B
  // x_bf16 scratch lives in d_out (134 MB): dead before GEMM3 writes out.
  bf16_t* xb = (bf16_t*)d_out;                         // 65536*512 bf16 = 67108864 B

  hipMemsetAsync(kv_num, 0, 532480, stream);           // kv_num + kv_den

  xcast_kernel<<<dim3(NTOK * DIMC / 8 / 256), dim3(256), 0, stream>>>(x, xb);
  wprep_kernel<<<dim3(256), dim3(256), 0, stream>>>(W_in, b_in, Wq, Wk, Wv, WcT, bias_c);

  // GEMM1: xb [65536,512] @ WcT -> qkv1 [65536,1024] bf16 (exp on k cols)
  gemm_kernel<1><<<dim3(8, 512, 1), dim3(256), 0, stream>>>(
      xb, WcT, (void*)qkv1, bias_c,
      512 /*K*/, 512 /*lda*/, NCOL /*ldc*/, (size_t)0, (size_t)0, (size_t)0);

  kv_accum_kernel<<<dim3(16, HEADS, BATCH), dim3(256), 0, stream>>>(qkv1, kv_num, kv_den);
  softmax_q_kernel<<<dim3(NTOK * HEADS / 256), dim3(256), 0, stream>>>(qkv1);
  mprep_kernel<<<dim3(BATCH * HEADS), dim3(512), 0, stream>>>(kv_num, kv_den, W_out, Mt);

  // GEMM3 (batched over b): q [8192,256](bf16, lda=1024) @ Mt[b] -> out [8192,512] f32
  gemm_kernel<0><<<dim3(4, 64, BATCH), dim3(256), 0, stream>>>(
      qkv1, Mt, (void*)out, b_out,
      256 /*K*/, NCOL /*lda*/, DIMC /*ldc*/,
      (size_t)NSEQ * NCOL, (size_t)DIMC * 256, (size_t)NSEQ * DIMC);
}

// Round 3
// 526.612 us; speedup vs baseline: 1.1639x; 1.0057x over previous
//
#include <hip/hip_runtime.h>
#include <cstdint>
#include <cstddef>

typedef __bf16 bf16_t;
typedef __bf16 bf16x8 __attribute__((ext_vector_type(8)));
typedef __bf16 bf16x4 __attribute__((ext_vector_type(4)));
typedef float  f32x4  __attribute__((ext_vector_type(4)));

#define HEADS    8
#define DIM_HEAD 64
#define SLICE    32
#define DIMC     512      // DIM == INNER == 512
#define NCOL     1024     // q'(0..255) | expk(256..511) | v(512..1023)
#define BATCH    8
#define NSEQ     8192
#define NTOK     65536

// Async global->LDS, 16B per lane. LDS dest is wave-uniform base + lane*16.
__device__ __forceinline__ void gl2lds16(const bf16_t* g, bf16_t* l) {
  __builtin_amdgcn_global_load_lds(
      (const __attribute__((address_space(1))) uint32_t*)g,
      (__attribute__((address_space(3))) uint32_t*)l, 16, 0, 0);
}

// ---------------------------------------------------------------------------
// x fp32 -> bf16 (xb lives in d_out scratch; dead before GEMM3 writes out)
// ---------------------------------------------------------------------------
__global__ __launch_bounds__(256) void xcast_kernel(const float* __restrict__ x,
                                                    bf16_t* __restrict__ xb) {
  const size_t i = ((size_t)blockIdx.x * 256 + threadIdx.x) * 8;
  const float4 a = *reinterpret_cast<const float4*>(x + i);
  const float4 b = *reinterpret_cast<const float4*>(x + i + 4);
  bf16x8 w;
  w[0] = (bf16_t)a.x; w[1] = (bf16_t)a.y; w[2] = (bf16_t)a.z; w[3] = (bf16_t)a.w;
  w[4] = (bf16_t)b.x; w[5] = (bf16_t)b.y; w[6] = (bf16_t)b.z; w[7] = (bf16_t)b.w;
  *reinterpret_cast<bf16x8*>(xb + i) = w;
}

// ---------------------------------------------------------------------------
// Weight prep: WcT[col][cin] (bf16) with Wq/Wk/Wv cached in LDS.
// ---------------------------------------------------------------------------
__global__ __launch_bounds__(256) void wprep_kernel(
    const float* __restrict__ W_in, const float* __restrict__ b_in,
    const float* __restrict__ Wq,   const float* __restrict__ Wk,
    const float* __restrict__ Wv,
    bf16_t* __restrict__ WcT, float* __restrict__ bias_c) {
  __shared__ float sW[8192];                 // Wq[0..2048) Wk[2048..4096) Wv[4096..8192)
  for (int t = threadIdx.x; t < 2048; t += 256) { sW[t] = Wq[t]; sW[2048 + t] = Wk[t]; }
  for (int t = threadIdx.x; t < 4096; t += 256) sW[4096 + t] = Wv[t];
  __syncthreads();

  const int T  = blockIdx.x * 256 + threadIdx.x;
  const int NT = gridDim.x * 256;
  for (int idx = T; idx < NCOL * DIMC; idx += NT) {
    const int col = idx >> 9, cin = idx & 511;
    int base, ldw, h, j;
    if (col < 256)      { h = col >> 5;       j = col & 31;       base = 0;    ldw = 32; }
    else if (col < 512) { h = (col-256) >> 5; j = (col-256) & 31; base = 2048; ldw = 32; }
    else                { h = (col-512) >> 6; j = (col-512) & 63; base = 4096; ldw = 64; }
    const float4* vp = reinterpret_cast<const float4*>(W_in + (size_t)cin * DIMC + h * DIM_HEAD);
    float acc = 0.f;
    #pragma unroll
    for (int d4 = 0; d4 < 16; ++d4) {
      const float4 v = vp[d4];
      acc += v.x * sW[base + (4*d4+0)*ldw + j];
      acc += v.y * sW[base + (4*d4+1)*ldw + j];
      acc += v.z * sW[base + (4*d4+2)*ldw + j];
      acc += v.w * sW[base + (4*d4+3)*ldw + j];
    }
    WcT[(size_t)col * DIMC + cin] = (bf16_t)acc;
  }
  if (T < NCOL) {
    const int col = T;
    int base, ldw, h, j;
    if (col < 256)      { h = col >> 5;       j = col & 31;       base = 0;    ldw = 32; }
    else if (col < 512) { h = (col-256) >> 5; j = (col-256) & 31; base = 2048; ldw = 32; }
    else                { h = (col-512) >> 6; j = (col-512) & 63; base = 4096; ldw = 64; }
    const float* vec = b_in + h * DIM_HEAD;
    float acc = 0.f;
    #pragma unroll 8
    for (int d = 0; d < DIM_HEAD; ++d) acc += vec[d] * sW[base + d * ldw + j];
    bias_c[col] = acc;
  }
}

// ---------------------------------------------------------------------------
// 128x128xBK64 MFMA GEMM (m97 structure, XOR-swizzled unpadded LDS,
// global_load_lds 16B staging) + XCD-aware block swizzle: all n-blocks of an
// m-slab land on the same XCD (xcd = linear_id % 8) so A is fetched into one
// L2 once instead of 8 (EPI=1) / 4 (EPI=0) times.
// EPI=1 (GEMM1): bf16 store; cols<256 -> fused softmax over each 32-col
//   h-group (shfl_xor over the 16-lane qd-group, 2 regs/lane); cols [256,512)
//   -> exp(); cols >=512 -> plain.
// EPI=0 (GEMM3): fp32 store + bias, batched via blockIdx.z.
// ---------------------------------------------------------------------------
template<int EPI>
__global__ __launch_bounds__(256) void gemm_kernel(
    const bf16_t* __restrict__ A, const bf16_t* __restrict__ Bt,
    void* __restrict__ Cv, const float* __restrict__ bias,
    int K, int lda, int ldc,
    size_t strideA, size_t strideB, size_t strideC)
{
  __shared__ bf16_t As[128 * 64];   // unpadded: required by global_load_lds
  __shared__ bf16_t Bs[128 * 64];
  const int tid = threadIdx.x;
  // XCD swizzle: linear id p (x fastest); same-m group => same (p % 8).
  const int p = blockIdx.y * gridDim.x + blockIdx.x;
  int mblk, nblk;
  if (EPI == 1) { mblk = (p & 7) + ((p >> 6) << 3); nblk = (p >> 3) & 7; }
  else          { mblk = (p & 7) + ((p >> 5) << 3); nblk = (p >> 3) & 3; }
  const int m0 = mblk * 128;
  const int n0 = nblk * 128;
  const int bz = blockIdx.z;
  const int wave = tid >> 6, lane = tid & 63;
  const int cg   = lane & 15, qd = lane >> 4;
  const int wm   = (wave & 1) * 64, wn = (wave >> 1) * 64;
  const int srow   = lane >> 3;
  const int gchunk = (lane & 7) ^ srow;     // XOR column-chunk swizzle
  const int chb    = cg & 7;

  const bf16_t* Ab = A  + strideA * bz;
  const bf16_t* Bb = Bt + strideB * bz;

  f32x4 acc[4][4];
  #pragma unroll
  for (int i = 0; i < 4; ++i)
    #pragma unroll
    for (int j = 0; j < 4; ++j) acc[i][j] = (f32x4){0.f, 0.f, 0.f, 0.f};

  for (int k0 = 0; k0 < K; k0 += 64) {
    __syncthreads();
    #pragma unroll
    for (int i = 0; i < 4; ++i) {
      const int c = wave * 4 + i;
      const int row = c * 8 + srow;
      gl2lds16(Ab + (size_t)(m0 + row) * lda + k0 + gchunk * 8, As + c * 512 + lane * 8);
    }
    #pragma unroll
    for (int i = 0; i < 4; ++i) {
      const int c = wave * 4 + i;
      const int row = c * 8 + srow;
      gl2lds16(Bb + (size_t)(n0 + row) * K + k0 + gchunk * 8, Bs + c * 512 + lane * 8);
    }
    __syncthreads();
    #pragma unroll
    for (int ks = 0; ks < 64; ks += 32) {
      const int k4 = ks >> 3;
      bf16x8 af[4], bfr[4];
      #pragma unroll
      for (int i = 0; i < 4; ++i) {
        const int ch = (qd + k4) ^ chb;
        af[i] = *reinterpret_cast<const bf16x8*>(As + (wm + 16*i + cg) * 64 + ch * 8);
      }
      #pragma unroll
      for (int j = 0; j < 4; ++j) {
        const int ch = (qd + k4) ^ chb;
        bfr[j] = *reinterpret_cast<const bf16x8*>(Bs + (wn + 16*j + cg) * 64 + ch * 8);
      }
      #pragma unroll
      for (int i = 0; i < 4; ++i)
        #pragma unroll
        for (int j = 0; j < 4; ++j)
          acc[i][j] = __builtin_amdgcn_mfma_f32_16x16x32_bf16(af[i], bfr[j], acc[i][j], 0, 0, 0);
    }
  }

  if (EPI == 1 && n0 < 256) {
    // Fused softmax(q): each h-group = 32 cols = regs j0,j1 over the 16-lane
    // qd-group. shfl_xor masks 1..8 only touch lane bits [3:0] -> stay in group.
    #pragma unroll
    for (int jp = 0; jp < 2; ++jp) {
      const int j0 = 2 * jp, j1 = 2 * jp + 1;
      const float b0 = bias[n0 + wn + 16 * j0 + cg];
      const float b1 = bias[n0 + wn + 16 * j1 + cg];
      #pragma unroll
      for (int i = 0; i < 4; ++i) {
        #pragma unroll
        for (int rr = 0; rr < 4; ++rr) {
          float v0 = acc[i][j0][rr] + b0;
          float v1 = acc[i][j1][rr] + b1;
          float mx = fmaxf(v0, v1);
          #pragma unroll
          for (int d = 1; d < 16; d <<= 1) mx = fmaxf(mx, __shfl_xor(mx, d, 64));
          const float e0 = __expf(v0 - mx), e1 = __expf(v1 - mx);
          float s = e0 + e1;
          #pragma unroll
          for (int d = 1; d < 16; d <<= 1) s += __shfl_xor(s, d, 64);
          const float rs = 1.f / s;
          const int row = m0 + wm + 16 * i + qd * 4 + rr;
          bf16_t* crow = (bf16_t*)Cv + (size_t)row * ldc;
          crow[n0 + wn + 16 * j0 + cg] = (bf16_t)(e0 * rs);
          crow[n0 + wn + 16 * j1 + cg] = (bf16_t)(e1 * rs);
        }
      }
    }
  } else {
    #pragma unroll
    for (int j = 0; j < 4; ++j) {
      const int col = n0 + wn + 16 * j + cg;
      const float bv = bias[col];
      #pragma unroll
      for (int i = 0; i < 4; ++i) {
        #pragma unroll
        for (int rr = 0; rr < 4; ++rr) {
          const int row = m0 + wm + 16 * i + qd * 4 + rr;
          float v = acc[i][j][rr] + bv;
          if (EPI == 1) {
            if (col < 512) v = __expf(v);   // exp(k) (n0>=256 here)
            ((bf16_t*)Cv + strideC * bz)[(size_t)row * ldc + col] = (bf16_t)v;
          } else {
            ((float*)Cv + strideC * bz)[(size_t)row * ldc + col] = v;
          }
        }
      }
    }
  }
}

// ---------------------------------------------------------------------------
// kv accumulation: per (b,h): num[s][c] = sum_n expk[n,s]*v[n,c]; den[s] = sum expk.
// ---------------------------------------------------------------------------
__global__ __launch_bounds__(256) void kv_accum_kernel(const bf16_t* __restrict__ qkv1,
                                                       float* __restrict__ kv_num,
                                                       float* __restrict__ kv_den) {
  const int chunk = blockIdx.x;                 // 16 chunks over NSEQ
  const int h = blockIdx.y, b = blockIdx.z;
  const int tid = threadIdx.x;
  const int wave = tid >> 6, lane = tid & 63;
  const int cgrp = lane & 15, sgrp = lane >> 4;
  const int c0 = cgrp * 4, s0 = sgrp * 8;

  float acc[8][4];
  float dacc[8];
  #pragma unroll
  for (int i = 0; i < 8; ++i) {
    dacc[i] = 0.f;
    #pragma unroll
    for (int j = 0; j < 4; ++j) acc[i][j] = 0.f;
  }

  const int nbase = chunk * 512 + wave * 128;
  const bf16_t* base = qkv1 + ((size_t)(b * NSEQ + nbase)) * NCOL;
  const int ek_off = 256 + h * SLICE + s0;
  const int v_off  = 512 + h * DIM_HEAD + c0;

  #pragma unroll 4
  for (int n = 0; n < 128; ++n) {
    const bf16_t* rowp = base + (size_t)n * NCOL;
    bf16x8 ek = *reinterpret_cast<const bf16x8*>(rowp + ek_off);
    bf16x4 vv = *reinterpret_cast<const bf16x4*>(rowp + v_off);
    float ekf[8], vf[4];
    #pragma unroll
    for (int i = 0; i < 8; ++i) ekf[i] = (float)ek[i];
    #pragma unroll
    for (int j = 0; j < 4; ++j) vf[j] = (float)vv[j];
    #pragma unroll
    for (int i = 0; i < 8; ++i) {
      dacc[i] += ekf[i];
      #pragma unroll
      for (int j = 0; j < 4; ++j) acc[i][j] += ekf[i] * vf[j];
    }
  }

  __shared__ float red[4][SLICE][DIM_HEAD];   // 32 KB
  __shared__ float redd[4][SLICE];
  #pragma unroll
  for (int i = 0; i < 8; ++i)
    #pragma unroll
    for (int j = 0; j < 4; ++j) red[wave][s0 + i][c0 + j] = acc[i][j];
  if (cgrp == 0) {
    #pragma unroll
    for (int i = 0; i < 8; ++i) redd[wave][s0 + i] = dacc[i];
  }
  __syncthreads();
  float* dstn = kv_num + (size_t)(b * HEADS + h) * (SLICE * DIM_HEAD);
  for (int t = tid; t < SLICE * DIM_HEAD; t += 256) {
    const int s = t >> 6, c = t & 63;
    atomicAdd(&dstn[t], red[0][s][c] + red[1][s][c] + red[2][s][c] + red[3][s][c]);
  }
  if (tid < SLICE)
    atomicAdd(&kv_den[(b * HEADS + h) * SLICE + tid],
              redd[0][tid] + redd[1][tid] + redd[2][tid] + redd[3][tid]);
}

// ---------------------------------------------------------------------------
// M prep: Mt[b][outc][h*32+s] = sum_c (kv_num/den) * W_out[h*64+c][outc]
// ---------------------------------------------------------------------------
__global__ __launch_bounds__(512) void mprep_kernel(const float* __restrict__ kv_num,
                                                    const float* __restrict__ kv_den,
                                                    const float* __restrict__ W_out,
                                                    bf16_t* __restrict__ Mt) {
  const int bh = blockIdx.x, b = bh >> 3, h = bh & 7;
  const int tid = threadIdx.x;
  __shared__ float kvn[SLICE][DIM_HEAD];   // 8 KB (normalized kv)
  __shared__ float wbuf[8][DIMC];          // 16 KB
  const float* src = kv_num + (size_t)bh * (SLICE * DIM_HEAD);
  for (int t = tid; t < SLICE * DIM_HEAD; t += 512)
    kvn[t >> 6][t & 63] = src[t] / kv_den[bh * SLICE + (t >> 6)];
  float accs[SLICE];
  #pragma unroll
  for (int s = 0; s < SLICE; ++s) accs[s] = 0.f;
  for (int cb = 0; cb < DIM_HEAD; cb += 8) {
    __syncthreads();
    for (int t = tid; t < 8 * DIMC; t += 512)
      wbuf[t >> 9][t & 511] = W_out[(size_t)(h * DIM_HEAD + cb + (t >> 9)) * DIMC + (t & 511)];
    __syncthreads();
    #pragma unroll
    for (int cc = 0; cc < 8; ++cc) {
      const float wv = wbuf[cc][tid];
      #pragma unroll
      for (int s = 0; s < SLICE; ++s) accs[s] += kvn[s][cb + cc] * wv;
    }
  }
  bf16_t* dst = Mt + (size_t)b * (DIMC * 256) + (size_t)tid * 256 + h * SLICE;
  #pragma unroll
  for (int s = 0; s < SLICE; ++s) dst[s] = (bf16_t)accs[s];
}

// ---------------------------------------------------------------------------
extern "C" void kernel_launch(void* const* d_in, const int* in_sizes, int n_in,
                              void* d_out, int out_size, void* d_ws, size_t ws_size,
                              hipStream_t stream) {
  const float* x     = (const float*)d_in[0];
  const float* W_in  = (const float*)d_in[1];
  const float* b_in  = (const float*)d_in[2];
  const float* Wq    = (const float*)d_in[3];
  const float* Wk    = (const float*)d_in[4];
  const float* Wv    = (const float*)d_in[5];
  const float* W_out = (const float*)d_in[6];
  const float* b_out = (const float*)d_in[7];

  uint8_t* ws = (uint8_t*)d_ws;
  bf16_t* qkv1   = (bf16_t*)(ws);                      // 65536*1024 bf16 = 134217728 B
  bf16_t* WcT    = (bf16_t*)(ws + 134217728ull);       // 1024*512 bf16  = 1048576 B
  float*  bias_c = (float*) (ws + 135266304ull);       // 1024 f32       = 4096 B
  float*  kv_num = (float*) (ws + 135270400ull);       // 8*8*32*64 f32  = 524288 B
  float*  kv_den = (float*) (ws + 135794688ull);       // 8*8*32 f32     = 8192 B
  bf16_t* Mt     = (bf16_t*)(ws + 135802880ull);       // 8*512*256 bf16 = 2097152 B
  // x_bf16 scratch lives in d_out (134 MB): dead before GEMM3 writes out.
  bf16_t* xb = (bf16_t*)d_out;                         // 65536*512 bf16 = 67108864 B

  hipMemsetAsync(kv_num, 0, 532480, stream);           // kv_num + kv_den

  xcast_kernel<<<dim3(NTOK * DIMC / 8 / 256), dim3(256), 0, stream>>>(x, xb);
  wprep_kernel<<<dim3(256), dim3(256), 0, stream>>>(W_in, b_in, Wq, Wk, Wv, WcT, bias_c);

  // GEMM1: xb [65536,512] @ WcT -> qkv1 [65536,1024] bf16
  // (fused softmax on q cols, exp on k cols)
  gemm_kernel<1><<<dim3(8, 512, 1), dim3(256), 0, stream>>>(
      xb, WcT, (void*)qkv1, bias_c,
      512 /*K*/, 512 /*lda*/, NCOL /*ldc*/, (size_t)0, (size_t)0, (size_t)0);

  kv_accum_kernel<<<dim3(16, HEADS, BATCH), dim3(256), 0, stream>>>(qkv1, kv_num, kv_den);
  mprep_kernel<<<dim3(BATCH * HEADS), dim3(512), 0, stream>>>(kv_num, kv_den, W_out, Mt);

  // GEMM3 (batched over b): q' [8192,256](bf16, lda=1024) @ Mt[b] -> out [8192,512] f32
  gemm_kernel<0><<<dim3(4, 64, BATCH), dim3(256), 0, stream>>>(
      qkv1, Mt, d_out, b_out,
      256 /*K*/, NCOL /*lda*/, DIMC /*ldc*/,
      (size_t)NSEQ * NCOL, (size_t)DIMC * 256, (size_t)NSEQ * DIMC);
}